// Round 18
// baseline (164.863 us; speedup 1.0000x reference)
//
#include <hip/hip_runtime.h>
#include <stdint.h>

#define D_ 384
#define NPTS 4096
// ws float-index layout:
#define W4_OFF   0         // 32*16*384
#define W8_OFF   196608    // 32*64*384
#define W16_OFF  983040    // 32*256*384  (ends 4128768)
#define CW_OFF   4128768   // 96*384 current-center rows
#define ZV_OFF   4165632   // 96*8 slice argmax values
#define ZI_OFF   4166400   // 96*8 slice argmax indices (int)
#define FA_OFF   4167168   // 96*4 slice-done counters (int)
#define FB_OFF   4167552   // 96*4 center-ready flags (int), ends 4167936

#define AGENT __HIP_MEMORY_SCOPE_AGENT

// ---------------- Threefry-2x32 (JAX-exact, 20 rounds) ----------------
__device__ __forceinline__ void tf_round(uint32_t& x0, uint32_t& x1, int r) {
  x0 += x1;
  x1 = (x1 << r) | (x1 >> (32 - r));
  x1 ^= x0;
}

__device__ void tf2x32(uint32_t k0, uint32_t k1, uint32_t x0, uint32_t x1,
                       uint32_t& y0, uint32_t& y1) {
  uint32_t ks2 = k0 ^ k1 ^ 0x1BD11BDAu;
  x0 += k0; x1 += k1;
  tf_round(x0, x1, 13); tf_round(x0, x1, 15); tf_round(x0, x1, 26); tf_round(x0, x1, 6);
  x0 += k1; x1 += ks2 + 1u;
  tf_round(x0, x1, 17); tf_round(x0, x1, 29); tf_round(x0, x1, 16); tf_round(x0, x1, 24);
  x0 += ks2; x1 += k0 + 2u;
  tf_round(x0, x1, 13); tf_round(x0, x1, 15); tf_round(x0, x1, 26); tf_round(x0, x1, 6);
  x0 += k0; x1 += k1 + 3u;
  tf_round(x0, x1, 17); tf_round(x0, x1, 29); tf_round(x0, x1, 16); tf_round(x0, x1, 24);
  x0 += k1; x1 += ks2 + 4u;
  tf_round(x0, x1, 13); tf_round(x0, x1, 15); tf_round(x0, x1, 26); tf_round(x0, x1, 6);
  x0 += ks2; x1 += k0 + 5u;
  y0 = x0; y1 = x1;
}

// ---------------- pool16: MEASURED ~31 us, HBM floor. Done. ----------------
__global__ __launch_bounds__(384) void pool16_kernel(const float* __restrict__ feats,
                                                     float* __restrict__ ws) {
  int blk = blockIdx.x;
  int b = blk >> 6;
  int cell = ((blk & 63) << 2) + threadIdx.y;
  int q = threadIdx.x;                 // 0..95
  int ch = cell >> 4, cw = cell & 15;
  const float* fb = feats + (size_t)b * NPTS * D_;
  float ax = 0.f, ay = 0.f, az = 0.f, aw = 0.f;
  #pragma unroll
  for (int dh = 0; dh < 4; ++dh) {
    int h = ch * 4 + dh;
    #pragma unroll
    for (int dw = 0; dw < 4; ++dw) {
      int w = cw * 4 + dw;
      float4 v = *(const float4*)(fb + ((size_t)(h * 64 + w)) * D_ + q * 4);
      ax += v.x; ay += v.y; az += v.z; aw += v.w;
    }
  }
  float4 o = { ax * (1.f/16.f), ay * (1.f/16.f), az * (1.f/16.f), aw * (1.f/16.f) };
  *(float4*)(ws + W16_OFF + ((size_t)(b * 256 + cell)) * D_ + q * 4) = o;
}

// -------- pool_rest (R12-proven): w8 AND w4 from w16; also zeroes flags --------
__global__ __launch_bounds__(256) void pool_rest_kernel(float* __restrict__ ws) {
  if (blockIdx.x == 0) {
    int* iw = (int*)ws;
    for (int i = threadIdx.x; i < 768; i += 256) iw[FA_OFF + i] = 0;  // FA+FB contiguous
  }
  int gid = blockIdx.x * 256 + threadIdx.x;
  if (gid < 196608) {
    int q = gid % 96;
    int c8 = (gid / 96) & 63;
    int b = gid / (96 * 64);
    int p = c8 >> 3, r = c8 & 7;
    const float4* w16b = (const float4*)(ws + W16_OFF + (size_t)b * 256 * D_);
    float ax = 0.f, ay = 0.f, az = 0.f, aw = 0.f;
    #pragma unroll
    for (int a = 0; a < 2; ++a)
      #pragma unroll
      for (int c = 0; c < 2; ++c) {
        int cell = (p * 2 + a) * 16 + (r * 2 + c);
        float4 v = w16b[(size_t)cell * 96 + q];
        ax += v.x; ay += v.y; az += v.z; aw += v.w;
      }
    float4 o = { ax * 0.25f, ay * 0.25f, az * 0.25f, aw * 0.25f };
    *(float4*)(ws + W8_OFF + ((size_t)(b * 64 + c8)) * D_ + q * 4) = o;
  } else {
    int idx = gid - 196608;            // 0..49151
    int q = idx % 96;
    int c4 = (idx / 96) & 15;
    int b = idx / (96 * 16);
    int p = c4 >> 2, r = c4 & 3;
    const float4* w16b = (const float4*)(ws + W16_OFF + (size_t)b * 256 * D_);
    float ax = 0.f, ay = 0.f, az = 0.f, aw = 0.f;
    #pragma unroll
    for (int a = 0; a < 2; ++a)
      #pragma unroll
      for (int c = 0; c < 2; ++c) {
        int p8 = p * 2 + a, r8 = r * 2 + c;
        float bx = 0.f, by = 0.f, bz = 0.f, bw = 0.f;
        #pragma unroll
        for (int a2 = 0; a2 < 2; ++a2)
          #pragma unroll
          for (int c2 = 0; c2 < 2; ++c2) {
            int cell = (p8 * 2 + a2) * 16 + (r8 * 2 + c2);
            float4 v = w16b[(size_t)cell * 96 + q];
            bx += v.x; by += v.y; bz += v.z; bw += v.w;
          }
        bx *= 0.25f; by *= 0.25f; bz *= 0.25f; bw *= 0.25f;
        ax += bx; ay += by; az += bz; aw += bw;
      }
    float4 o = { ax * 0.25f, ay * 0.25f, az * 0.25f, aw * 0.25f };
    *(float4*)(ws + W4_OFF + ((size_t)(b * 16 + c4)) * D_ + q * 4) = o;
  }
}

// ---- km_coop: k-means++ spread over 448 blocks (352 slices + 96 pickers) ----
// Per-CU pull <= 49 KB (was 393). Per-(b,si) handoff via device-scope atomics;
// co-residency: 51KB LDS -> 3 blocks/CU -> capacity 768 >= 448 (no deadlock).
__global__ __launch_bounds__(256) void km_coop(float* __restrict__ ws,
                                               float* __restrict__ out) {
  int blk = blockIdx.x;
  int tid = threadIdx.x;
  int* iws = (int*)ws;

  if (blk >= 352) {
    // ======================= PICKER (wave 0 only) =======================
    if (tid >= 64) return;
    int pk = blk - 352;                 // 0..95
    int si = pk >> 5, b = pk & 31;
    int bsi = si * 32 + b;
    int n   = (si == 0) ? 16 : (si == 1) ? 64 : 256;
    int nsl = (si == 2) ? 8 : (si == 1) ? 2 : 1;
    const float* tier = ws + ((si == 0) ? (size_t)W4_OFF  + (size_t)b * 16  * D_
                         : (si == 1) ? (size_t)W8_OFF  + (size_t)b * 64  * D_
                                     : (size_t)W16_OFF + (size_t)b * 256 * D_);
    float* cw = ws + CW_OFF + (size_t)bsi * D_;
    float* ob = out + ((size_t)b * 12 + si * 4) * D_;
    int* fA = iws + FA_OFF + bsi * 4;
    int* fB = iws + FB_OFF + bsi * 4;

    // seed s0 (R9 lane-parallel; lane 3 computes idx0)
    int s;
    {
      uint32_t f0, f1, bk0, bk1, r0, r1, s0, s1, e0, e1;
      tf2x32(0u, 42u, 0u, (uint32_t)si, f0, f1);
      tf2x32(f0, f1, 0u, (uint32_t)b, bk0, bk1);
      uint32_t cC = (tid < 3) ? 1u : 0u;
      tf2x32(bk0, bk1, 0u, cC, r0, r1);
      uint32_t cD = (tid < 3) ? (uint32_t)tid : 1u;
      tf2x32(r0, r1, 0u, cD, s0, s1);
      tf2x32(s0, s1, 0u, 0u, e0, e1);
      int cand = (int)((e0 ^ e1) & (uint32_t)(n - 1));
      s = __shfl(cand, 3);
    }

    for (int t = 0; t < 4; ++t) {
      // copy winning tier row -> out[t] (+ cw for slices)
      for (int j = tid; j < D_; j += 64) {
        float v = tier[(size_t)s * D_ + j];
        ob[(size_t)t * D_ + j] = v;
        if (t < 3) __hip_atomic_store(&cw[j], v, __ATOMIC_RELAXED, AGENT);
      }
      if (t == 3) break;
      __threadfence();                      // wave-wide vmcnt drain (single wave)
      if (tid == 0) __hip_atomic_store(&fB[t], 1, __ATOMIC_RELEASE, AGENT);
      // wait for all slices of phase t
      int snew = 0;
      if (tid == 0) {
        while (__hip_atomic_load(&fA[t], __ATOMIC_ACQUIRE, AGENT) < nsl)
          __builtin_amdgcn_s_sleep(1);
        float bz = -1e38f; int bi = 0;
        for (int sl = 0; sl < nsl; ++sl) {
          float zr = __hip_atomic_load(&ws[ZV_OFF + bsi * 8 + sl], __ATOMIC_RELAXED, AGENT);
          int   ir = __hip_atomic_load(&iws[ZI_OFF + bsi * 8 + sl], __ATOMIC_RELAXED, AGENT);
          if (sl == 0 || zr > bz || (zr == bz && ir < bi)) { bz = zr; bi = ir; }
        }
        snew = bi;
      }
      s = __shfl(snew, 0);
    }
    return;
  }

  // ========================== SLICE ==========================
  int si, b, sl, rows;
  if (blk < 256)      { si = 2; b = blk >> 3;          sl = blk & 7; rows = 32; }
  else if (blk < 320) { si = 1; b = (blk - 256) >> 1;  sl = (blk - 256) & 1; rows = 32; }
  else                { si = 0; b = blk - 320;         sl = 0; rows = 16; }
  int bsi = si * 32 + b;
  int rowbase = sl * 32;
  const float* tier = ws + ((si == 0) ? (size_t)W4_OFF  + (size_t)b * 16  * D_
                       : (si == 1) ? (size_t)W8_OFF  + (size_t)b * 64  * D_
                                   : (size_t)W16_OFF + (size_t)b * 256 * D_);
  const float* cw = ws + CW_OFF + (size_t)bsi * D_;
  int* fA = iws + FA_OFF + bsi * 4;
  int* fB = iws + FB_OFF + bsi * 4;

  __shared__ float L[32][385];       // rows (padded: 385%32=1 -> conflict-free)
  __shared__ float csh[D_];
  __shared__ float pc[8][33];
  __shared__ float msq[32];
  __shared__ uint32_t skey[3][2];

  // load own rows into LDS (coalesced; <=49 KB pull)
  for (int i = tid; i < rows * D_; i += 256) {
    int r = i / D_, c = i - r * D_;
    L[r][c] = tier[(size_t)(rowbase + r) * D_ + c];
  }
  // step keys (R9 seeding, skey part only)
  if (tid < 64) {
    uint32_t f0, f1, bk0, bk1, r0, r1, s0, s1;
    tf2x32(0u, 42u, 0u, (uint32_t)si, f0, f1);
    tf2x32(f0, f1, 0u, (uint32_t)b, bk0, bk1);
    uint32_t cC = (tid < 3) ? 1u : 0u;
    tf2x32(bk0, bk1, 0u, cC, r0, r1);
    uint32_t cD = (tid < 3) ? (uint32_t)tid : 1u;
    tf2x32(r0, r1, 0u, cD, s0, s1);
    if (tid < 3) { skey[tid][0] = s0; skey[tid][1] = s1; }
  }
  __syncthreads();

  const float TINY = __uint_as_float(0x00800000u);
  int r = tid & 31, part = tid >> 5;   // 8 parts x 32 rows

  #pragma unroll 1
  for (int t = 0; t < 3; ++t) {
    // wait center t ready
    if (tid == 0) {
      while (__hip_atomic_load(&fB[t], __ATOMIC_ACQUIRE, AGENT) == 0)
        __builtin_amdgcn_s_sleep(1);
    }
    __syncthreads();
    // stage center into LDS (L1-bypassing loads)
    if (tid < 64) {
      for (int j = tid; j < D_; j += 64)
        csh[j] = __hip_atomic_load(&cw[j], __ATOMIC_RELAXED, AGENT);
    }
    __syncthreads();
    // partial distances
    float acc = 0.f;
    if (r < rows) {
      #pragma unroll
      for (int j = 0; j < 48; ++j) {
        float d = L[r][part * 48 + j] - csh[part * 48 + j];
        acc += d * d;
      }
    }
    pc[part][r] = acc;
    __syncthreads();
    // row totals + min + gumbel z (threads 0..31), wave-0 argmax
    if (tid < 64) {
      float z = -1e38f; int gi = rowbase + tid;
      if (tid < rows) {
        float d = ((pc[0][tid] + pc[1][tid]) + (pc[2][tid] + pc[3][tid]))
                + ((pc[4][tid] + pc[5][tid]) + (pc[6][tid] + pc[7][tid]));
        float m = (t == 0) ? d : fminf(msq[tid], d);
        msq[tid] = m;
        uint32_t y0, y1;
        tf2x32(skey[t][0], skey[t][1], 0u, (uint32_t)gi, y0, y1);
        uint32_t bits = y0 ^ y1;
        float f = __uint_as_float((bits >> 9) | 0x3F800000u) - 1.0f;
        float u = (f > 0.f) ? f : TINY;
        z = -__logf(-__logf(u)) + __logf(m);    // m==0 -> -inf, never wins
      }
      float bv = z; int bi = gi;
      #pragma unroll
      for (int m2 = 1; m2 < 64; m2 <<= 1) {
        float ov = __shfl_xor(bv, m2);
        int   oi = __shfl_xor(bi, m2);
        if (ov > bv || (ov == bv && oi < bi)) { bv = ov; bi = oi; }
      }
      if (tid == 0) {
        __hip_atomic_store(&ws[ZV_OFF + bsi * 8 + sl], bv, __ATOMIC_RELAXED, AGENT);
        __hip_atomic_store(&iws[ZI_OFF + bsi * 8 + sl], bi, __ATOMIC_RELAXED, AGENT);
        __hip_atomic_fetch_add(&fA[t], 1, __ATOMIC_RELEASE, AGENT);
      }
    }
    __syncthreads();
  }
}

extern "C" void kernel_launch(void* const* d_in, const int* in_sizes, int n_in,
                              void* d_out, int out_size, void* d_ws, size_t ws_size,
                              hipStream_t stream) {
  const float* feats = (const float*)d_in[0];
  float* out = (float*)d_out;
  float* ws  = (float*)d_ws;   // uses ~16.7 MB

  pool16_kernel<<<2048, dim3(96, 4, 1), 0, stream>>>(feats, ws);
  pool_rest_kernel<<<960, 256, 0, stream>>>(ws);
  km_coop<<<448, 256, 0, stream>>>(ws, out);
}

// Round 19
// 107.189 us; speedup vs baseline: 1.5381x; 1.5381x over previous
//
#include <hip/hip_runtime.h>
#include <stdint.h>

#define D_ 384
#define NPTS 4096
// ws layout (floats): w4 [32*16*384] @0, w8 [32*64*384] @196608, w16 [32*256*384] @983040
#define W4_OFF 0
#define W8_OFF 196608
#define W16_OFF 983040

// ---------------- Threefry-2x32 (JAX-exact, 20 rounds) ----------------
__device__ __forceinline__ void tf_round(uint32_t& x0, uint32_t& x1, int r) {
  x0 += x1;
  x1 = (x1 << r) | (x1 >> (32 - r));
  x1 ^= x0;
}

// NOINLINE: one body in the binary (v9 is code-size-minimized; 6 inlined copies
// of this ~400B body were a large share of the I$ footprint).
__device__ __attribute__((noinline)) uint2 tf2x32(uint32_t k0, uint32_t k1,
                                                  uint32_t x0, uint32_t x1) {
  uint32_t ks2 = k0 ^ k1 ^ 0x1BD11BDAu;
  x0 += k0; x1 += k1;
  tf_round(x0, x1, 13); tf_round(x0, x1, 15); tf_round(x0, x1, 26); tf_round(x0, x1, 6);
  x0 += k1; x1 += ks2 + 1u;
  tf_round(x0, x1, 17); tf_round(x0, x1, 29); tf_round(x0, x1, 16); tf_round(x0, x1, 24);
  x0 += ks2; x1 += k0 + 2u;
  tf_round(x0, x1, 13); tf_round(x0, x1, 15); tf_round(x0, x1, 26); tf_round(x0, x1, 6);
  x0 += k0; x1 += k1 + 3u;
  tf_round(x0, x1, 17); tf_round(x0, x1, 29); tf_round(x0, x1, 16); tf_round(x0, x1, 24);
  x0 += k1; x1 += ks2 + 4u;
  tf_round(x0, x1, 13); tf_round(x0, x1, 15); tf_round(x0, x1, 26); tf_round(x0, x1, 6);
  x0 += ks2; x1 += k0 + 5u;
  return make_uint2(x0, x1);
}

// ---------------- pool16: MEASURED ~31 us, HBM floor. Done. ----------------
__global__ __launch_bounds__(384) void pool16_kernel(const float* __restrict__ feats,
                                                     float* __restrict__ ws) {
  int blk = blockIdx.x;
  int b = blk >> 6;
  int cell = ((blk & 63) << 2) + threadIdx.y;
  int q = threadIdx.x;                 // 0..95
  int ch = cell >> 4, cw = cell & 15;
  const float* fb = feats + (size_t)b * NPTS * D_;
  float ax = 0.f, ay = 0.f, az = 0.f, aw = 0.f;
  #pragma unroll
  for (int dh = 0; dh < 4; ++dh) {
    int h = ch * 4 + dh;
    #pragma unroll
    for (int dw = 0; dw < 4; ++dw) {
      int w = cw * 4 + dw;
      float4 v = *(const float4*)(fb + ((size_t)(h * 64 + w)) * D_ + q * 4);
      ax += v.x; ay += v.y; az += v.z; aw += v.w;
    }
  }
  float4 o = { ax * (1.f/16.f), ay * (1.f/16.f), az * (1.f/16.f), aw * (1.f/16.f) };
  *(float4*)(ws + W16_OFF + ((size_t)(b * 256 + cell)) * D_ + q * 4) = o;
}

// ---------------- pool_rest (R12-proven): w8 AND w4 from w16 ----------------
__global__ __launch_bounds__(256) void pool_rest_kernel(float* __restrict__ ws) {
  int gid = blockIdx.x * 256 + threadIdx.x;
  if (gid < 196608) {
    int q = gid % 96;
    int c8 = (gid / 96) & 63;
    int b = gid / (96 * 64);
    int p = c8 >> 3, r = c8 & 7;
    const float4* w16b = (const float4*)(ws + W16_OFF + (size_t)b * 256 * D_);
    float ax = 0.f, ay = 0.f, az = 0.f, aw = 0.f;
    #pragma unroll
    for (int a = 0; a < 2; ++a)
      #pragma unroll
      for (int c = 0; c < 2; ++c) {
        int cell = (p * 2 + a) * 16 + (r * 2 + c);
        float4 v = w16b[(size_t)cell * 96 + q];
        ax += v.x; ay += v.y; az += v.z; aw += v.w;
      }
    float4 o = { ax * 0.25f, ay * 0.25f, az * 0.25f, aw * 0.25f };
    *(float4*)(ws + W8_OFF + ((size_t)(b * 64 + c8)) * D_ + q * 4) = o;
  } else {
    int idx = gid - 196608;            // 0..49151
    int q = idx % 96;
    int c4 = (idx / 96) & 15;
    int b = idx / (96 * 16);
    int p = c4 >> 2, r = c4 & 3;
    const float4* w16b = (const float4*)(ws + W16_OFF + (size_t)b * 256 * D_);
    float ax = 0.f, ay = 0.f, az = 0.f, aw = 0.f;   // w4 accum
    #pragma unroll
    for (int a = 0; a < 2; ++a)
      #pragma unroll
      for (int c = 0; c < 2; ++c) {
        int p8 = p * 2 + a, r8 = r * 2 + c;
        float bx = 0.f, by = 0.f, bz = 0.f, bw = 0.f; // w8 accum (fresh, like pool8)
        #pragma unroll
        for (int a2 = 0; a2 < 2; ++a2)
          #pragma unroll
          for (int c2 = 0; c2 < 2; ++c2) {
            int cell = (p8 * 2 + a2) * 16 + (r8 * 2 + c2);
            float4 v = w16b[(size_t)cell * 96 + q];
            bx += v.x; by += v.y; bz += v.z; bw += v.w;
          }
        bx *= 0.25f; by *= 0.25f; bz *= 0.25f; bw *= 0.25f;
        ax += bx; ay += by; az += bz; aw += bw;
      }
    float4 o = { ax * 0.25f, ay * 0.25f, az * 0.25f, aw * 0.25f };
    *(float4*)(ws + W4_OFF + ((size_t)(b * 16 + c4)) * D_ + q * 4) = o;
  }
}

// ------- k-means++ v9: R12-v5 semantics with MINIMAL CODE FOOTPRINT -------
// All 48-iter loops rolled (#pragma unroll 1): x rows re-read from L2 inside
// the loop — identical data path to what the compiler produced for v5
// (R11: VGPR=120, rows rematerialized). FP order identical to v5 -> bit-exact.
// threefry noinline. Target text ~2KB (was ~20-30KB) -> I$ cold-walk gone.
__global__ __launch_bounds__(512) void kmeans_kernel(const float* __restrict__ ws,
                                                     float* __restrict__ out) {
  int blk = blockIdx.x;
  int si = blk >> 5;
  int b  = blk & 31;
  int n  = (si == 0) ? 16 : (si == 1) ? 64 : 256;

  const float* pooled;
  if (si == 0)      pooled = ws + W4_OFF  + (size_t)b * 16  * D_;
  else if (si == 1) pooled = ws + W8_OFF  + (size_t)b * 64  * D_;
  else              pooled = ws + W16_OFF + (size_t)b * 256 * D_;
  float* ob = out + ((size_t)b * 12 + si * 4) * D_;

  __shared__ __align__(16) float4 csh4[98];   // padded: part*49+k
  __shared__ float minsq[256];
  __shared__ uint32_t skey[3][2];
  __shared__ int sidx0;
  __shared__ float wmaxv[4];
  __shared__ int   wmaxi[4];

  int tid  = threadIdx.x;
  int row  = tid >> 1;        // 0..255
  int part = tid & 1;         // half-row owner
  int lane = tid & 63;
  int wv   = tid >> 6;

  const float4* rp = (const float4*)(pooled + (size_t)row * D_ + part * 192);

  if (tid < 256) minsq[tid] = 0.f;

  // ---- seeding: wave 0, branch-free lane-parallel threefry (R9-proven) ----
  if (tid < 64) {
    uint2 f  = tf2x32(0u, 42u, 0u, (uint32_t)si);
    uint2 bk = tf2x32(f.x, f.y, 0u, (uint32_t)b);
    uint32_t cC = (tid < 3) ? 1u : 0u;
    uint2 r1 = tf2x32(bk.x, bk.y, 0u, cC);            // lanes 0-2: k1; lane 3: k0
    uint32_t cD = (tid < 3) ? (uint32_t)tid : 1u;
    uint2 s1 = tf2x32(r1.x, r1.y, 0u, cD);            // lanes 0-2: skey[t]; lane 3: q
    uint2 e1 = tf2x32(s1.x, s1.y, 0u, 0u);            // lane 3: l
    if (tid < 3) { skey[tid][0] = s1.x; skey[tid][1] = s1.y; }
    else if (tid == 3) sidx0 = (int)((e1.x ^ e1.y) & (uint32_t)(n - 1));
  }
  __syncthreads();                                     // B1

  // ---- c0 broadcast: owners copy global -> LDS + out (rolled) ----
  int s = sidx0;
  if (row == s) {
    #pragma unroll 1
    for (int k = 0; k < 48; ++k) {
      float4 v = rp[k];
      csh4[part * 49 + k] = v;
      ((float4*)(ob + part * 192))[k] = v;
    }
  }
  __syncthreads();                                     // B2

  // ---- min_sq = ||x - c0||^2 (rolled; x streamed from L2) ----
  if (row < n) {
    float acc = 0.f;
    #pragma unroll 1
    for (int k = 0; k < 48; ++k) {
      float4 x = rp[k], c4 = csh4[part * 49 + k];
      float dx = x.x - c4.x, dy = x.y - c4.y;
      float dz = x.z - c4.z, dw = x.w - c4.w;
      acc += dx * dx; acc += dy * dy; acc += dz * dz; acc += dw * dw;
    }
    acc += __shfl_xor(acc, 1);
    if (part == 0) minsq[row] = acc;
  }
  __syncthreads();                                     // B3

  const float TINY = __uint_as_float(0x00800000u);  // f32 tiny

  #pragma unroll 1
  for (int t = 0; t < 3; ++t) {
    // --- z = gumbel + log(minsq); per-wave argmax (no sum/div phase) ---
    if (tid < 256) {
      float z = -1e30f;
      if (tid < n) {
        float m = minsq[tid];
        uint2 y = tf2x32(skey[t][0], skey[t][1], 0u, (uint32_t)tid);
        uint32_t bits = y.x ^ y.y;
        float f = __uint_as_float((bits >> 9) | 0x3F800000u) - 1.0f;
        float u = (f > 0.f) ? f : TINY;
        z = -__logf(-__logf(u)) + __logf(m);   // m==0 -> -inf, never wins
      }
      float bv = z; int bi = tid;
      #pragma unroll
      for (int m2 = 1; m2 < 64; m2 <<= 1) {
        float ov = __shfl_xor(bv, m2);
        int   oi = __shfl_xor(bi, m2);
        if (ov > bv || (ov == bv && oi < bi)) { bv = ov; bi = oi; }
      }
      if (lane == 0) { wmaxv[wv] = bv; wmaxi[wv] = bi; }
    }
    __syncthreads();                                   // B4

    // --- all threads combine redundantly ---
    float cv = wmaxv[0]; int ci = wmaxi[0];
    #pragma unroll
    for (int w2 = 1; w2 < 4; ++w2)
      if (wmaxv[w2] > cv || (wmaxv[w2] == cv && wmaxi[w2] < ci)) { cv = wmaxv[w2]; ci = wmaxi[w2]; }
    s = ci;

    // --- owners write out (+ csh only if another distance pass follows) ---
    if (row == s) {
      #pragma unroll 1
      for (int k = 0; k < 48; ++k) {
        float4 v = rp[k];
        ((float4*)(ob + (size_t)(t + 1) * D_ + part * 192))[k] = v;
        if (t < 2) csh4[part * 49 + k] = v;
      }
    }
    if (t < 2) {
      __syncthreads();                                 // B5
      if (row < n) {
        float acc = 0.f;
        #pragma unroll 1
        for (int k = 0; k < 48; ++k) {
          float4 x = rp[k], c4 = csh4[part * 49 + k];
          float dx = x.x - c4.x, dy = x.y - c4.y;
          float dz = x.z - c4.z, dw = x.w - c4.w;
          acc += dx * dx; acc += dy * dy; acc += dz * dz; acc += dw * dw;
        }
        acc += __shfl_xor(acc, 1);
        if (part == 0) minsq[row] = fminf(minsq[row], acc);
      }
      __syncthreads();                                 // B6
    }
  }
}

extern "C" void kernel_launch(void* const* d_in, const int* in_sizes, int n_in,
                              void* d_out, int out_size, void* d_ws, size_t ws_size,
                              hipStream_t stream) {
  const float* feats = (const float*)d_in[0];
  float* out = (float*)d_out;
  float* ws  = (float*)d_ws;   // uses 16,515,072 bytes

  pool16_kernel<<<2048, dim3(96, 4, 1), 0, stream>>>(feats, ws);
  pool_rest_kernel<<<960, 256, 0, stream>>>(ws);
  kmeans_kernel<<<96, 512, 0, stream>>>(ws, out);
}